// Round 3
// baseline (472.563 us; speedup 1.0000x reference)
//
#include <hip/hip_runtime.h>

#define NH 1024   // hidden
#define NI2 2048  // 2*intermediate
#define NI 1024   // intermediate
#define NE 16     // experts
#define NT 1024   // tokens (2*512)

static constexpr float LIMITF = 7.0f;
static constexpr float ALPHAF = 1.702f;
static constexpr float EPSF = 1e-5f;

typedef short bf16x8 __attribute__((ext_vector_type(8)));
typedef float f32x16 __attribute__((ext_vector_type(16)));

__device__ __forceinline__ unsigned short f2bf(float f) {
  unsigned int u = __builtin_bit_cast(unsigned int, f);
  u = (u + 0x7FFFu + ((u >> 16) & 1u)) >> 16;
  return (unsigned short)u;
}

// ---------------- out = x (residual base) ----------------
__global__ __launch_bounds__(256) void k_init(const float* __restrict__ x,
                                              float* __restrict__ out) {
  int i = blockIdx.x * 256 + threadIdx.x;
  reinterpret_cast<float4*>(out)[i] = reinterpret_cast<const float4*>(x)[i];
}

// ---------------- RMSNorm + router ----------------
__global__ __launch_bounds__(256) void k_norm_router(
    const float* __restrict__ x, const float* __restrict__ nsc,
    const float* __restrict__ wg, const float* __restrict__ bg,
    unsigned short* __restrict__ xn, int* __restrict__ topk_idx,
    float* __restrict__ topk_gate, int* __restrict__ counts) {
  int t = blockIdx.x;
  int tid = threadIdx.x;
  int wave = tid >> 6, lane = tid & 63;

  float4 v = reinterpret_cast<const float4*>(x + (size_t)t * NH)[tid];
  float ss = v.x * v.x + v.y * v.y + v.z * v.z + v.w * v.w;
  for (int off = 32; off; off >>= 1) ss += __shfl_xor(ss, off);

  __shared__ float red[4];
  __shared__ float redl[4][16];
  __shared__ float logits_s[16];
  if (lane == 0) red[wave] = ss;
  __syncthreads();
  float tot = red[0] + red[1] + red[2] + red[3];
  float r = rsqrtf(tot * (1.0f / NH) + EPSF);

  float4 sc = reinterpret_cast<const float4*>(nsc)[tid];
  float xv[4];
  xv[0] = v.x * r * sc.x;
  xv[1] = v.y * r * sc.y;
  xv[2] = v.z * r * sc.z;
  xv[3] = v.w * r * sc.w;

  ushort4 o;
  o.x = f2bf(xv[0]); o.y = f2bf(xv[1]); o.z = f2bf(xv[2]); o.w = f2bf(xv[3]);
  reinterpret_cast<ushort4*>(xn + (size_t)t * NH)[tid] = o;

  float acc[16];
#pragma unroll
  for (int e = 0; e < 16; e++) acc[e] = 0.f;
  int hbase = tid * 4;
#pragma unroll
  for (int i = 0; i < 4; i++) {
    const float4* wr = reinterpret_cast<const float4*>(wg + (size_t)(hbase + i) * NE);
#pragma unroll
    for (int j = 0; j < 4; j++) {
      float4 w = wr[j];
      acc[j * 4 + 0] += xv[i] * w.x;
      acc[j * 4 + 1] += xv[i] * w.y;
      acc[j * 4 + 2] += xv[i] * w.z;
      acc[j * 4 + 3] += xv[i] * w.w;
    }
  }
#pragma unroll
  for (int e = 0; e < 16; e++)
    for (int off = 32; off; off >>= 1) acc[e] += __shfl_xor(acc[e], off);
  if (lane == 0) {
#pragma unroll
    for (int e = 0; e < 16; e++) redl[wave][e] = acc[e];
  }
  __syncthreads();
  if (tid < 16)
    logits_s[tid] = redl[0][tid] + redl[1][tid] + redl[2][tid] + redl[3][tid] + bg[tid];
  __syncthreads();

  if (tid == 0) {
    float vals[16];
#pragma unroll
    for (int e = 0; e < 16; e++) vals[e] = logits_s[e];
    int sel[4]; float sv[4];
    unsigned used = 0;
    for (int k = 0; k < 4; k++) {
      float best = -1e30f; int bi = 0;
      for (int e = 0; e < 16; e++) {
        if (!((used >> e) & 1u) && vals[e] > best) { best = vals[e]; bi = e; }
      }
      used |= 1u << bi; sel[k] = bi; sv[k] = best;
    }
    float g[4], ssum = 0.f;
    for (int k = 0; k < 4; k++) { g[k] = __expf(sv[k] - sv[0]); ssum += g[k]; }
    for (int k = 0; k < 4; k++) {
      topk_idx[t * 4 + k] = sel[k];
      topk_gate[t * 4 + k] = g[k] / ssum;
      atomicAdd(&counts[sel[k]], 1);
    }
  }
}

// ---------------- prefix scan over 16 experts ----------------
__global__ void k_scan(const int* __restrict__ counts, int* __restrict__ offsets,
                       int* __restrict__ cursor) {
  if (blockIdx.x == 0 && threadIdx.x == 0) {
    int o = 0;
    for (int e = 0; e < NE; e++) { offsets[e] = o; cursor[e] = o; o += counts[e]; }
  }
}

// ---------------- fill compact per-expert row lists ----------------
__global__ __launch_bounds__(256) void k_fill(const int* __restrict__ topk_idx,
                                              const float* __restrict__ topk_gate,
                                              int* __restrict__ cursor,
                                              int* __restrict__ rows_tok,
                                              float* __restrict__ rows_gate) {
  int idx = blockIdx.x * 256 + threadIdx.x;
  if (idx >= NT * 4) return;
  int e = topk_idx[idx];
  int slot = atomicAdd(&cursor[e], 1);
  rows_tok[slot] = idx >> 2;
  rows_gate[slot] = topk_gate[idx];
}

// ---------------- FFN1: (expert, 32-col strip), K double-buffered --------
// LDS: 2 buffers x [kc 0..15][col 0..31][8] bf16 = 16 KB total.
__global__ __launch_bounds__(256, 4) void k_ffn1(
    const unsigned short* __restrict__ xn, const float* __restrict__ w1,
    const float* __restrict__ b1, const int* __restrict__ counts,
    const int* __restrict__ offsets, const int* __restrict__ rows_tok,
    unsigned short* __restrict__ s_buf) {
  int e = blockIdx.y;
  int cnt = counts[e];
  if (cnt == 0) return;
  int n0 = blockIdx.x * 32;
  int rowbase = offsets[e];
  int tid = threadIdx.x;

  __shared__ __align__(16) unsigned short lds_b[2 * 16 * 32 * 8];

  const float* w1e = w1 + (size_t)e * (NH * NI2) + n0;
  int col = tid & 31, kc8 = tid >> 5;  // kc8 0..7

  int lane = tid & 63, wave = tid >> 6;
  int lrow = lane & 31, khalf = lane >> 5;
  float bias = b1[(size_t)e * NI2 + n0 + lrow];
  int parity = lrow & 1;

  for (int m0 = 0; m0 < cnt; m0 += 256) {
    int tb0 = m0 + wave * 32;
    int tb1 = m0 + 128 + wave * 32;
    bool dual = (m0 + 128) < cnt;
    int tok0 = rows_tok[rowbase + min(tb0 + lrow, cnt - 1)];
    const unsigned short* a0p = xn + (size_t)tok0 * NH;
    const unsigned short* a1p = a0p;
    if (dual) {
      int tok1 = rows_tok[rowbase + min(tb1 + lrow, cnt - 1)];
      a1p = xn + (size_t)tok1 * NH;
    }

    f32x16 acc0 = {0.f,0.f,0.f,0.f,0.f,0.f,0.f,0.f,0.f,0.f,0.f,0.f,0.f,0.f,0.f,0.f};
    f32x16 acc1 = {0.f,0.f,0.f,0.f,0.f,0.f,0.f,0.f,0.f,0.f,0.f,0.f,0.f,0.f,0.f,0.f};

    __syncthreads();  // LDS reuse guard across m-chunks
    // prologue: stage tile 0 into buf 0
#pragma unroll
    for (int half = 0; half < 2; half++) {
      int kcz = kc8 + half * 8;
      int kb = kcz * 8;
      float f[8];
#pragma unroll
      for (int j = 0; j < 8; j++) f[j] = w1e[(size_t)(kb + j) * NI2 + col];
      unsigned pk[4];
#pragma unroll
      for (int j = 0; j < 4; j++)
        pk[j] = (unsigned)f2bf(f[2 * j]) | ((unsigned)f2bf(f[2 * j + 1]) << 16);
      *reinterpret_cast<uint4*>(&lds_b[(size_t)(kcz * 32 + col) * 8]) =
          *reinterpret_cast<const uint4*>(pk);
    }
    __syncthreads();

    int buf = 0;
    for (int kt = 0; kt < 8; kt++) {
      float fst[2][8];
      if (kt < 7) {
        int k0n = (kt + 1) * 128;
#pragma unroll
        for (int half = 0; half < 2; half++) {
          int kb = (kc8 + half * 8) * 8;
#pragma unroll
          for (int j = 0; j < 8; j++)
            fst[half][j] = w1e[(size_t)(k0n + kb + j) * NI2 + col];
        }
      }
      const unsigned short* ab0 = a0p + kt * 128 + khalf * 8;
      const unsigned short* ab1 = a1p + kt * 128 + khalf * 8;
#pragma unroll
      for (int k2 = 0; k2 < 8; k2++) {
        bf16x8 bv = *reinterpret_cast<const bf16x8*>(
            &lds_b[(size_t)(((buf * 16) + k2 * 2 + khalf) * 32 + lrow) * 8]);
        bf16x8 av0 = *reinterpret_cast<const bf16x8*>(ab0 + k2 * 16);
        acc0 = __builtin_amdgcn_mfma_f32_32x32x16_bf16(av0, bv, acc0, 0, 0, 0);
        if (dual) {
          bf16x8 av1 = *reinterpret_cast<const bf16x8*>(ab1 + k2 * 16);
          acc1 = __builtin_amdgcn_mfma_f32_32x32x16_bf16(av1, bv, acc1, 0, 0, 0);
        }
      }
      if (kt < 7) {
        int nb = buf ^ 1;
#pragma unroll
        for (int half = 0; half < 2; half++) {
          int kcz = kc8 + half * 8;
          unsigned pk[4];
#pragma unroll
          for (int j = 0; j < 4; j++)
            pk[j] = (unsigned)f2bf(fst[half][2 * j]) |
                    ((unsigned)f2bf(fst[half][2 * j + 1]) << 16);
          *reinterpret_cast<uint4*>(
              &lds_b[(size_t)((nb * 16 + kcz) * 32 + col) * 8]) =
              *reinterpret_cast<const uint4*>(pk);
        }
        __syncthreads();
        buf = nb;
      }
    }

#pragma unroll
    for (int t2 = 0; t2 < 2; t2++) {
      if (t2 == 1 && !dual) break;
      f32x16 acc = t2 ? acc1 : acc0;
      int tb = t2 ? tb1 : tb0;
#pragma unroll
      for (int reg = 0; reg < 16; reg++) {
        float v = acc[reg] + bias;
        float p = __shfl_xor(v, 1);
        int row = (reg & 3) + 8 * (reg >> 2) + 4 * khalf;
        int m = tb + row;
        if (!parity && m < cnt) {
          float aa = fminf(v, LIMITF);
          float bb = fminf(fmaxf(p, -LIMITF), LIMITF);
          float sig = 1.0f / (1.0f + __expf(-ALPHAF * aa));
          float sval = aa * sig * (bb + 1.0f);
          s_buf[(size_t)(rowbase + m) * NI + ((n0 + lrow) >> 1)] = f2bf(sval);
        }
      }
    }
  }
}

// ---------------- FFN2: (expert, 32-col strip, K-half), double-buffered --
__global__ __launch_bounds__(256, 4) void k_ffn2(
    const unsigned short* __restrict__ s_buf, const float* __restrict__ w2,
    const float* __restrict__ b2, const int* __restrict__ counts,
    const int* __restrict__ offsets, const int* __restrict__ rows_tok,
    const float* __restrict__ rows_gate, float* __restrict__ out) {
  int e = blockIdx.y;
  int cnt = counts[e];
  if (cnt == 0) return;
  int n0 = blockIdx.x * 32;
  int ks = blockIdx.z;         // K half: [ks*512, ks*512+512)
  int rowbase = offsets[e];
  int tid = threadIdx.x;

  __shared__ __align__(16) unsigned short lds_b[2 * 16 * 32 * 8];

  const float* w2e = w2 + (size_t)e * (NI * NH) + n0;
  int col = tid & 31, kc8 = tid >> 5;
  int kbase = ks * 512;

  int lane = tid & 63, wave = tid >> 6;
  int lrow = lane & 31, khalf = lane >> 5;
  float b2v = (ks == 0) ? b2[(size_t)e * NH + n0 + lrow] : 0.f;

  for (int m0 = 0; m0 < cnt; m0 += 256) {
    int tb0 = m0 + wave * 32;
    int tb1 = m0 + 128 + wave * 32;
    bool dual = (m0 + 128) < cnt;
    int r0 = rowbase + min(tb0 + lrow, cnt - 1);
    const unsigned short* a0p = s_buf + (size_t)r0 * NI + kbase;
    const unsigned short* a1p = a0p;
    if (dual) {
      int r1 = rowbase + min(tb1 + lrow, cnt - 1);
      a1p = s_buf + (size_t)r1 * NI + kbase;
    }

    f32x16 acc0 = {0.f,0.f,0.f,0.f,0.f,0.f,0.f,0.f,0.f,0.f,0.f,0.f,0.f,0.f,0.f,0.f};
    f32x16 acc1 = {0.f,0.f,0.f,0.f,0.f,0.f,0.f,0.f,0.f,0.f,0.f,0.f,0.f,0.f,0.f,0.f};

    __syncthreads();
#pragma unroll
    for (int half = 0; half < 2; half++) {
      int kcz = kc8 + half * 8;
      int kb = kcz * 8;
      float f[8];
#pragma unroll
      for (int j = 0; j < 8; j++)
        f[j] = w2e[(size_t)(kbase + kb + j) * NH + col];
      unsigned pk[4];
#pragma unroll
      for (int j = 0; j < 4; j++)
        pk[j] = (unsigned)f2bf(f[2 * j]) | ((unsigned)f2bf(f[2 * j + 1]) << 16);
      *reinterpret_cast<uint4*>(&lds_b[(size_t)(kcz * 32 + col) * 8]) =
          *reinterpret_cast<const uint4*>(pk);
    }
    __syncthreads();

    int buf = 0;
    for (int kt = 0; kt < 4; kt++) {
      float fst[2][8];
      if (kt < 3) {
        int k0n = kbase + (kt + 1) * 128;
#pragma unroll
        for (int half = 0; half < 2; half++) {
          int kb = (kc8 + half * 8) * 8;
#pragma unroll
          for (int j = 0; j < 8; j++)
            fst[half][j] = w2e[(size_t)(k0n + kb + j) * NH + col];
        }
      }
      const unsigned short* ab0 = a0p + kt * 128 + khalf * 8;
      const unsigned short* ab1 = a1p + kt * 128 + khalf * 8;
#pragma unroll
      for (int k2 = 0; k2 < 8; k2++) {
        bf16x8 bv = *reinterpret_cast<const bf16x8*>(
            &lds_b[(size_t)(((buf * 16) + k2 * 2 + khalf) * 32 + lrow) * 8]);
        bf16x8 av0 = *reinterpret_cast<const bf16x8*>(ab0 + k2 * 16);
        acc0 = __builtin_amdgcn_mfma_f32_32x32x16_bf16(av0, bv, acc0, 0, 0, 0);
        if (dual) {
          bf16x8 av1 = *reinterpret_cast<const bf16x8*>(ab1 + k2 * 16);
          acc1 = __builtin_amdgcn_mfma_f32_32x32x16_bf16(av1, bv, acc1, 0, 0, 0);
        }
      }
      if (kt < 3) {
        int nb = buf ^ 1;
#pragma unroll
        for (int half = 0; half < 2; half++) {
          int kcz = kc8 + half * 8;
          unsigned pk[4];
#pragma unroll
          for (int j = 0; j < 4; j++)
            pk[j] = (unsigned)f2bf(fst[half][2 * j]) |
                    ((unsigned)f2bf(fst[half][2 * j + 1]) << 16);
          *reinterpret_cast<uint4*>(
              &lds_b[(size_t)((nb * 16 + kcz) * 32 + col) * 8]) =
              *reinterpret_cast<const uint4*>(pk);
        }
        __syncthreads();
        buf = nb;
      }
    }

#pragma unroll
    for (int t2 = 0; t2 < 2; t2++) {
      if (t2 == 1 && !dual) break;
      f32x16 acc = t2 ? acc1 : acc0;
      int tb = t2 ? tb1 : tb0;
#pragma unroll
      for (int reg = 0; reg < 16; reg++) {
        int row = (reg & 3) + 8 * (reg >> 2) + 4 * khalf;
        int m = tb + row;
        if (m < cnt) {
          int rr = rowbase + m;
          int tok = rows_tok[rr];
          float g = rows_gate[rr];
          atomicAdd(&out[(size_t)tok * NH + n0 + lrow], g * (acc[reg] + b2v));
        }
      }
    }
  }
}

extern "C" void kernel_launch(void* const* d_in, const int* in_sizes, int n_in,
                              void* d_out, int out_size, void* d_ws, size_t ws_size,
                              hipStream_t stream) {
  const float* x   = (const float*)d_in[0];
  const float* nsc = (const float*)d_in[1];
  const float* wg  = (const float*)d_in[2];
  const float* bg  = (const float*)d_in[3];
  const float* w1  = (const float*)d_in[4];
  const float* b1  = (const float*)d_in[5];
  const float* w2  = (const float*)d_in[6];
  const float* b2  = (const float*)d_in[7];
  float* out = (float*)d_out;
  char* ws = (char*)d_ws;

  int*   counts    = (int*)(ws + 0);
  int*   offsets   = (int*)(ws + 64);
  int*   cursor    = (int*)(ws + 128);
  int*   topk_idx  = (int*)(ws + 1024);
  float* topk_gate = (float*)(ws + 1024 + 16384);
  int*   rows_tok  = (int*)(ws + 1024 + 32768);
  float* rows_gate = (float*)(ws + 1024 + 49152);
  unsigned short* xn    = (unsigned short*)(ws + 131072);           // 2 MB
  unsigned short* s_buf = (unsigned short*)(ws + 4 * 1024 * 1024);  // 8 MB

  hipMemsetAsync(ws, 0, 256, stream);
  k_init<<<NT * NH / 1024, 256, 0, stream>>>(x, out);
  k_norm_router<<<NT, 256, 0, stream>>>(x, nsc, wg, bg, xn, topk_idx, topk_gate,
                                        counts);
  k_scan<<<1, 64, 0, stream>>>(counts, offsets, cursor);
  k_fill<<<16, 256, 0, stream>>>(topk_idx, topk_gate, cursor, rows_tok, rows_gate);
  k_ffn1<<<dim3(NI2 / 32, NE), 256, 0, stream>>>(xn, w1, b1, counts, offsets,
                                                 rows_tok, s_buf);
  k_ffn2<<<dim3(NH / 32, NE, 2), 256, 0, stream>>>(s_buf, w2, b2, counts, offsets,
                                                   rows_tok, rows_gate, out);
}

// Round 4
// 457.841 us; speedup vs baseline: 1.0322x; 1.0322x over previous
//
#include <hip/hip_runtime.h>

#define NH 1024   // hidden
#define NI2 2048  // 2*intermediate
#define NI 1024   // intermediate
#define NE 16     // experts
#define NT 1024   // tokens (2*512)
#define MAXSLOT 4608  // 4096 + 16*31 padding, rounded
#define MAXTILE 144   // MAXSLOT/32

static constexpr float LIMITF = 7.0f;
static constexpr float ALPHAF = 1.702f;
static constexpr float EPSF = 1e-5f;

typedef short bf16x8 __attribute__((ext_vector_type(8)));
typedef float f32x16 __attribute__((ext_vector_type(16)));

__device__ __forceinline__ unsigned short f2bf(float f) {
  unsigned int u = __builtin_bit_cast(unsigned int, f);
  u = (u + 0x7FFFu + ((u >> 16) & 1u)) >> 16;
  return (unsigned short)u;
}

// ---------------- RMSNorm + router ----------------
__global__ __launch_bounds__(256) void k_norm_router(
    const float* __restrict__ x, const float* __restrict__ nsc,
    const float* __restrict__ wg, const float* __restrict__ bg,
    unsigned short* __restrict__ xn, int* __restrict__ topk_idx,
    float* __restrict__ topk_gate, int* __restrict__ counts) {
  int t = blockIdx.x;
  int tid = threadIdx.x;
  int wave = tid >> 6, lane = tid & 63;

  float4 v = reinterpret_cast<const float4*>(x + (size_t)t * NH)[tid];
  float ss = v.x * v.x + v.y * v.y + v.z * v.z + v.w * v.w;
  for (int off = 32; off; off >>= 1) ss += __shfl_xor(ss, off);

  __shared__ float red[4];
  __shared__ float redl[4][16];
  __shared__ float logits_s[16];
  if (lane == 0) red[wave] = ss;
  __syncthreads();
  float tot = red[0] + red[1] + red[2] + red[3];
  float r = rsqrtf(tot * (1.0f / NH) + EPSF);

  float4 sc = reinterpret_cast<const float4*>(nsc)[tid];
  float xv[4];
  xv[0] = v.x * r * sc.x;
  xv[1] = v.y * r * sc.y;
  xv[2] = v.z * r * sc.z;
  xv[3] = v.w * r * sc.w;

  ushort4 o;
  o.x = f2bf(xv[0]); o.y = f2bf(xv[1]); o.z = f2bf(xv[2]); o.w = f2bf(xv[3]);
  reinterpret_cast<ushort4*>(xn + (size_t)t * NH)[tid] = o;

  float acc[16];
#pragma unroll
  for (int e = 0; e < 16; e++) acc[e] = 0.f;
  int hbase = tid * 4;
#pragma unroll
  for (int i = 0; i < 4; i++) {
    const float4* wr = reinterpret_cast<const float4*>(wg + (size_t)(hbase + i) * NE);
#pragma unroll
    for (int j = 0; j < 4; j++) {
      float4 w = wr[j];
      acc[j * 4 + 0] += xv[i] * w.x;
      acc[j * 4 + 1] += xv[i] * w.y;
      acc[j * 4 + 2] += xv[i] * w.z;
      acc[j * 4 + 3] += xv[i] * w.w;
    }
  }
#pragma unroll
  for (int e = 0; e < 16; e++)
    for (int off = 32; off; off >>= 1) acc[e] += __shfl_xor(acc[e], off);
  if (lane == 0) {
#pragma unroll
    for (int e = 0; e < 16; e++) redl[wave][e] = acc[e];
  }
  __syncthreads();
  if (tid < 16)
    logits_s[tid] = redl[0][tid] + redl[1][tid] + redl[2][tid] + redl[3][tid] + bg[tid];
  __syncthreads();

  if (tid == 0) {
    float vals[16];
#pragma unroll
    for (int e = 0; e < 16; e++) vals[e] = logits_s[e];
    int sel[4]; float sv[4];
    unsigned used = 0;
    for (int k = 0; k < 4; k++) {
      float best = -1e30f; int bi = 0;
      for (int e = 0; e < 16; e++) {
        if (!((used >> e) & 1u) && vals[e] > best) { best = vals[e]; bi = e; }
      }
      used |= 1u << bi; sel[k] = bi; sv[k] = best;
    }
    float g[4], ssum = 0.f;
    for (int k = 0; k < 4; k++) { g[k] = __expf(sv[k] - sv[0]); ssum += g[k]; }
    for (int k = 0; k < 4; k++) {
      topk_idx[t * 4 + k] = sel[k];
      topk_gate[t * 4 + k] = g[k] / ssum;
      atomicAdd(&counts[sel[k]], 1);
    }
  }
}

// ---------------- prefix scan (32-padded offsets) ----------------
__global__ void k_scan(const int* __restrict__ counts, int* __restrict__ offsets,
                       int* __restrict__ cursor) {
  if (blockIdx.x == 0 && threadIdx.x == 0) {
    int o = 0;
    for (int e = 0; e < NE; e++) {
      offsets[e] = o; cursor[e] = o;
      o += (counts[e] + 31) & ~31;
    }
    offsets[NE] = o;  // total padded slots
  }
}

// ---------------- fill compact per-expert row lists ----------------
__global__ __launch_bounds__(256) void k_fill(const int* __restrict__ topk_idx,
                                              const float* __restrict__ topk_gate,
                                              int* __restrict__ cursor,
                                              int* __restrict__ rows_tok,
                                              float* __restrict__ rows_gate,
                                              int* __restrict__ slot_of) {
  int idx = blockIdx.x * 256 + threadIdx.x;
  if (idx >= NT * 4) return;
  int e = topk_idx[idx];
  int slot = atomicAdd(&cursor[e], 1);
  rows_tok[slot] = idx >> 2;
  rows_gate[slot] = topk_gate[idx];
  slot_of[idx] = slot;
}

// ---------------- pad slots: tok=0, gate=0 ----------------
__global__ void k_pad(const int* __restrict__ counts, const int* __restrict__ offsets,
                      int* __restrict__ rows_tok, float* __restrict__ rows_gate) {
  int e = blockIdx.x;
  int start = offsets[e] + counts[e];
  int end = offsets[e] + ((counts[e] + 31) & ~31);
  int s = start + (int)threadIdx.x;
  if (s < end) { rows_tok[s] = 0; rows_gate[s] = 0.f; }
}

// ---------------- pack xn into MFMA A-fragment layout ----------------
// apack[tile][kstep 0..63][lane 0..63][8 bf16]; lane = khalf*32 + row,
// element = xn[rows_tok[tile*32+row]][kstep*16 + khalf*8 + j]
__global__ __launch_bounds__(256) void k_pack(
    const unsigned short* __restrict__ xn, const int* __restrict__ rows_tok,
    const int* __restrict__ offsets, unsigned short* __restrict__ apack) {
  int tile = blockIdx.x;
  if (tile * 32 >= offsets[NE]) return;
  int tid = threadIdx.x;
  int r = tid >> 3, s = tid & 7;
  int tok = rows_tok[tile * 32 + r];
  const unsigned short* src = xn + (size_t)tok * NH;
  int i0 = blockIdx.y * 4;
#pragma unroll
  for (int i = 0; i < 4; i++) {
    int k0 = (i0 + i) * 64 + s * 8;
    uint4 v = *reinterpret_cast<const uint4*>(src + k0);
    int kstep = k0 >> 4;
    int kh = s & 1;
    *reinterpret_cast<uint4*>(
        apack + ((size_t)(tile * 64 + kstep) * 64 + kh * 32 + r) * 8) = v;
  }
}

// ---------------- FFN1: (expert, 32-col strip); A from apack ------------
// Writes s in packed A-fragment layout (spack) for ffn2.
__global__ __launch_bounds__(256, 4) void k_ffn1(
    const unsigned short* __restrict__ apack, const float* __restrict__ w1,
    const float* __restrict__ b1, const int* __restrict__ counts,
    const int* __restrict__ offsets, unsigned short* __restrict__ spack) {
  int e = blockIdx.y;
  int cnt = counts[e];
  if (cnt == 0) return;
  int ntiles = (cnt + 31) >> 5;
  int tilebase = offsets[e] >> 5;
  int bx = blockIdx.x;  // n-strip / spack kstep
  int n0 = bx * 32;
  int tid = threadIdx.x;

  __shared__ __align__(16) unsigned short lds_b[2 * 16 * 32 * 8];  // 16 KB
  __shared__ __align__(16) unsigned short lds_t[4][32 * 16];       // 4 KB

  const float* w1e = w1 + (size_t)e * (NH * NI2) + n0;
  int col = tid & 31, kc8 = tid >> 5;

  int lane = tid & 63, wave = tid >> 6;
  int lrow = lane & 31, khalf = lane >> 5;
  float bias = b1[(size_t)e * NI2 + n0 + lrow];
  int parity = lrow & 1;

  for (int c0 = 0; c0 < ntiles; c0 += 8) {
    int t0 = c0 + wave, t1 = c0 + wave + 4;
    bool v0 = t0 < ntiles, v1 = t1 < ntiles;
    int at0 = v0 ? t0 : 0, at1 = v1 ? t1 : 0;
    const unsigned short* a0 =
        apack + ((size_t)(tilebase + at0) * 64 * 64 + lane) * 8;
    const unsigned short* a1 =
        apack + ((size_t)(tilebase + at1) * 64 * 64 + lane) * 8;

    f32x16 acc0 = {0.f,0.f,0.f,0.f,0.f,0.f,0.f,0.f,0.f,0.f,0.f,0.f,0.f,0.f,0.f,0.f};
    f32x16 acc1 = {0.f,0.f,0.f,0.f,0.f,0.f,0.f,0.f,0.f,0.f,0.f,0.f,0.f,0.f,0.f,0.f};

    __syncthreads();
    // prologue: stage K-tile 0
#pragma unroll
    for (int half = 0; half < 2; half++) {
      int kcz = kc8 + half * 8;
      int kb = kcz * 8;
      float f[8];
#pragma unroll
      for (int j = 0; j < 8; j++) f[j] = w1e[(size_t)(kb + j) * NI2 + col];
      unsigned pk[4];
#pragma unroll
      for (int j = 0; j < 4; j++)
        pk[j] = (unsigned)f2bf(f[2 * j]) | ((unsigned)f2bf(f[2 * j + 1]) << 16);
      *reinterpret_cast<uint4*>(&lds_b[(size_t)(kcz * 32 + col) * 8]) =
          *reinterpret_cast<const uint4*>(pk);
    }
    __syncthreads();

    int buf = 0;
    for (int kt = 0; kt < 8; kt++) {
      float fst[2][8];
      if (kt < 7) {
        int k0n = (kt + 1) * 128;
#pragma unroll
        for (int half = 0; half < 2; half++) {
          int kb = (kc8 + half * 8) * 8;
#pragma unroll
          for (int j = 0; j < 8; j++)
            fst[half][j] = w1e[(size_t)(k0n + kb + j) * NI2 + col];
        }
      }
      int ks0 = kt * 8;
#pragma unroll
      for (int k2 = 0; k2 < 8; k2++) {
        bf16x8 bv = *reinterpret_cast<const bf16x8*>(
            &lds_b[(size_t)(((buf * 16) + k2 * 2 + khalf) * 32 + lrow) * 8]);
        bf16x8 av0 =
            *reinterpret_cast<const bf16x8*>(a0 + (size_t)(ks0 + k2) * 512);
        acc0 = __builtin_amdgcn_mfma_f32_32x32x16_bf16(av0, bv, acc0, 0, 0, 0);
        bf16x8 av1 =
            *reinterpret_cast<const bf16x8*>(a1 + (size_t)(ks0 + k2) * 512);
        acc1 = __builtin_amdgcn_mfma_f32_32x32x16_bf16(av1, bv, acc1, 0, 0, 0);
      }
      if (kt < 7) {
        int nb = buf ^ 1;
#pragma unroll
        for (int half = 0; half < 2; half++) {
          int kcz = kc8 + half * 8;
          unsigned pk[4];
#pragma unroll
          for (int j = 0; j < 4; j++)
            pk[j] = (unsigned)f2bf(fst[half][2 * j]) |
                    ((unsigned)f2bf(fst[half][2 * j + 1]) << 16);
          *reinterpret_cast<uint4*>(
              &lds_b[(size_t)((nb * 16 + kcz) * 32 + col) * 8]) =
              *reinterpret_cast<const uint4*>(pk);
        }
        __syncthreads();
        buf = nb;
      }
    }

    // epilogue: swiglu -> LDS transpose -> packed-fragment store
#pragma unroll
    for (int t2 = 0; t2 < 2; t2++) {
      bool vv = t2 ? v1 : v0;
      int tt = t2 ? at1 : at0;
      f32x16 acc = t2 ? acc1 : acc0;
      __syncthreads();
#pragma unroll
      for (int reg = 0; reg < 16; reg++) {
        float v = acc[reg] + bias;
        float p = __shfl_xor(v, 1);
        if (!parity) {
          float aa = fminf(v, LIMITF);
          float bb = fminf(fmaxf(p, -LIMITF), LIMITF);
          float sig = 1.0f / (1.0f + __expf(-ALPHAF * aa));
          float sval = aa * sig * (bb + 1.0f);
          int row = (reg & 3) + 8 * (reg >> 2) + 4 * khalf;
          lds_t[wave][row * 16 + (lrow >> 1)] = f2bf(sval);
        }
      }
      __syncthreads();
      if (vv) {
        bf16x8 frag = *reinterpret_cast<const bf16x8*>(
            &lds_t[wave][(lane & 31) * 16 + (lane >> 5) * 8]);
        *reinterpret_cast<bf16x8*>(
            spack + ((size_t)((tilebase + tt) * 64 + bx) * 64 + lane) * 8) = frag;
      }
    }
  }
}

// ---------------- FFN2: (expert, 32-col strip); A from spack ------------
// Writes gate-scaled y_part[slot][h] fp32 (no atomics).
__global__ __launch_bounds__(256, 4) void k_ffn2(
    const unsigned short* __restrict__ spack, const float* __restrict__ w2,
    const float* __restrict__ b2, const int* __restrict__ counts,
    const int* __restrict__ offsets, const float* __restrict__ rows_gate,
    float* __restrict__ y_part) {
  int e = blockIdx.y;
  int cnt = counts[e];
  if (cnt == 0) return;
  int ntiles = (cnt + 31) >> 5;
  int tilebase = offsets[e] >> 5;
  int n0 = blockIdx.x * 32;
  int tid = threadIdx.x;

  __shared__ __align__(16) unsigned short lds_b[2 * 16 * 32 * 8];  // 16 KB
  __shared__ __align__(16) float lds_y[4][32 * 36];                // 18 KB

  const float* w2e = w2 + (size_t)e * (NI * NH) + n0;
  int col = tid & 31, kc8 = tid >> 5;

  int lane = tid & 63, wave = tid >> 6;
  int lrow = lane & 31, khalf = lane >> 5;
  float b2v = b2[(size_t)e * NH + n0 + lrow];

  for (int c0 = 0; c0 < ntiles; c0 += 8) {
    int t0 = c0 + wave, t1 = c0 + wave + 4;
    bool v0 = t0 < ntiles, v1 = t1 < ntiles;
    int at0 = v0 ? t0 : 0, at1 = v1 ? t1 : 0;
    const unsigned short* a0 =
        spack + ((size_t)(tilebase + at0) * 64 * 64 + lane) * 8;
    const unsigned short* a1 =
        spack + ((size_t)(tilebase + at1) * 64 * 64 + lane) * 8;

    f32x16 acc0 = {0.f,0.f,0.f,0.f,0.f,0.f,0.f,0.f,0.f,0.f,0.f,0.f,0.f,0.f,0.f,0.f};
    f32x16 acc1 = {0.f,0.f,0.f,0.f,0.f,0.f,0.f,0.f,0.f,0.f,0.f,0.f,0.f,0.f,0.f,0.f};

    __syncthreads();
#pragma unroll
    for (int half = 0; half < 2; half++) {
      int kcz = kc8 + half * 8;
      int kb = kcz * 8;
      float f[8];
#pragma unroll
      for (int j = 0; j < 8; j++) f[j] = w2e[(size_t)(kb + j) * NH + col];
      unsigned pk[4];
#pragma unroll
      for (int j = 0; j < 4; j++)
        pk[j] = (unsigned)f2bf(f[2 * j]) | ((unsigned)f2bf(f[2 * j + 1]) << 16);
      *reinterpret_cast<uint4*>(&lds_b[(size_t)(kcz * 32 + col) * 8]) =
          *reinterpret_cast<const uint4*>(pk);
    }
    __syncthreads();

    int buf = 0;
    for (int kt = 0; kt < 8; kt++) {
      float fst[2][8];
      if (kt < 7) {
        int k0n = (kt + 1) * 128;
#pragma unroll
        for (int half = 0; half < 2; half++) {
          int kb = (kc8 + half * 8) * 8;
#pragma unroll
          for (int j = 0; j < 8; j++)
            fst[half][j] = w2e[(size_t)(k0n + kb + j) * NH + col];
        }
      }
      int ks0 = kt * 8;
#pragma unroll
      for (int k2 = 0; k2 < 8; k2++) {
        bf16x8 bv = *reinterpret_cast<const bf16x8*>(
            &lds_b[(size_t)(((buf * 16) + k2 * 2 + khalf) * 32 + lrow) * 8]);
        bf16x8 av0 =
            *reinterpret_cast<const bf16x8*>(a0 + (size_t)(ks0 + k2) * 512);
        acc0 = __builtin_amdgcn_mfma_f32_32x32x16_bf16(av0, bv, acc0, 0, 0, 0);
        bf16x8 av1 =
            *reinterpret_cast<const bf16x8*>(a1 + (size_t)(ks0 + k2) * 512);
        acc1 = __builtin_amdgcn_mfma_f32_32x32x16_bf16(av1, bv, acc1, 0, 0, 0);
      }
      if (kt < 7) {
        int nb = buf ^ 1;
#pragma unroll
        for (int half = 0; half < 2; half++) {
          int kcz = kc8 + half * 8;
          unsigned pk[4];
#pragma unroll
          for (int j = 0; j < 4; j++)
            pk[j] = (unsigned)f2bf(fst[half][2 * j]) |
                    ((unsigned)f2bf(fst[half][2 * j + 1]) << 16);
          *reinterpret_cast<uint4*>(
              &lds_b[(size_t)((nb * 16 + kcz) * 32 + col) * 8]) =
              *reinterpret_cast<const uint4*>(pk);
        }
        __syncthreads();
        buf = nb;
      }
    }

    // epilogue: bias -> LDS transpose -> gate-scaled coalesced store
#pragma unroll
    for (int t2 = 0; t2 < 2; t2++) {
      bool vv = t2 ? v1 : v0;
      int tt = t2 ? at1 : at0;
      f32x16 acc = t2 ? acc1 : acc0;
      __syncthreads();
#pragma unroll
      for (int reg = 0; reg < 16; reg++) {
        int row = (reg & 3) + 8 * (reg >> 2) + 4 * khalf;
        lds_y[wave][row * 36 + lrow] = acc[reg] + b2v;
      }
      __syncthreads();
      if (vv) {
        int row = lane & 31, ch = lane >> 5;
        int slot = (tilebase + tt) * 32 + row;
        float g = rows_gate[slot];
        float* dst = y_part + (size_t)slot * NH + n0 + ch * 16;
#pragma unroll
        for (int q = 0; q < 4; q++) {
          float4 yv =
              *reinterpret_cast<const float4*>(&lds_y[wave][row * 36 + ch * 16 + q * 4]);
          yv.x *= g; yv.y *= g; yv.z *= g; yv.w *= g;
          reinterpret_cast<float4*>(dst)[q] = yv;
        }
      }
    }
  }
}

// ---------------- combine: out = x + sum_k y_part[slot_of[t,k]] ---------
__global__ __launch_bounds__(256) void k_combine(
    const float* __restrict__ x, const int* __restrict__ slot_of,
    const float* __restrict__ y_part, float* __restrict__ out) {
  int t = blockIdx.x;
  int tid = threadIdx.x;
  int s0 = slot_of[t * 4 + 0], s1 = slot_of[t * 4 + 1];
  int s2 = slot_of[t * 4 + 2], s3 = slot_of[t * 4 + 3];
  float4 r = reinterpret_cast<const float4*>(x + (size_t)t * NH)[tid];
  float4 a = reinterpret_cast<const float4*>(y_part + (size_t)s0 * NH)[tid];
  float4 b = reinterpret_cast<const float4*>(y_part + (size_t)s1 * NH)[tid];
  float4 c = reinterpret_cast<const float4*>(y_part + (size_t)s2 * NH)[tid];
  float4 d = reinterpret_cast<const float4*>(y_part + (size_t)s3 * NH)[tid];
  r.x += a.x + b.x + c.x + d.x;
  r.y += a.y + b.y + c.y + d.y;
  r.z += a.z + b.z + c.z + d.z;
  r.w += a.w + b.w + c.w + d.w;
  reinterpret_cast<float4*>(out + (size_t)t * NH)[tid] = r;
}

extern "C" void kernel_launch(void* const* d_in, const int* in_sizes, int n_in,
                              void* d_out, int out_size, void* d_ws, size_t ws_size,
                              hipStream_t stream) {
  const float* x   = (const float*)d_in[0];
  const float* nsc = (const float*)d_in[1];
  const float* wg  = (const float*)d_in[2];
  const float* bg  = (const float*)d_in[3];
  const float* w1  = (const float*)d_in[4];
  const float* b1  = (const float*)d_in[5];
  const float* w2  = (const float*)d_in[6];
  const float* b2  = (const float*)d_in[7];
  float* out = (float*)d_out;
  char* ws = (char*)d_ws;

  int*   counts    = (int*)(ws + 0);
  int*   offsets   = (int*)(ws + 128);   // 17 ints
  int*   cursor    = (int*)(ws + 256);
  int*   slot_of   = (int*)(ws + 4096);           // 16 KB
  int*   topk_idx  = (int*)(ws + 20480);          // 16 KB
  float* topk_gate = (float*)(ws + 36864);        // 16 KB
  int*   rows_tok  = (int*)(ws + 53248);          // 18 KB
  float* rows_gate = (float*)(ws + 71680);        // 18 KB
  unsigned short* xn    = (unsigned short*)(ws + (1u << 20));        // 2 MB
  unsigned short* apack = (unsigned short*)(ws + (4u << 20));        // 9 MB
  unsigned short* spack = (unsigned short*)(ws + (16u << 20));       // 9 MB
  float*          y_part = (float*)(ws + (28u << 20));               // 18 MB

  hipMemsetAsync(ws, 0, 512, stream);
  k_norm_router<<<NT, 256, 0, stream>>>(x, nsc, wg, bg, xn, topk_idx, topk_gate,
                                        counts);
  k_scan<<<1, 64, 0, stream>>>(counts, offsets, cursor);
  k_fill<<<16, 256, 0, stream>>>(topk_idx, topk_gate, cursor, rows_tok, rows_gate,
                                 slot_of);
  k_pad<<<16, 32, 0, stream>>>(counts, offsets, rows_tok, rows_gate);
  k_pack<<<dim3(MAXTILE, 4), 256, 0, stream>>>(xn, rows_tok, offsets, apack);
  k_ffn1<<<dim3(NI2 / 32, NE), 256, 0, stream>>>(apack, w1, b1, counts, offsets,
                                                 spack);
  k_ffn2<<<dim3(NH / 32, NE), 256, 0, stream>>>(spack, w2, b2, counts, offsets,
                                                rows_gate, y_part);
  k_combine<<<NT, 256, 0, stream>>>(x, slot_of, y_part, out);
}